// Round 1
// baseline (207.601 us; speedup 1.0000x reference)
//
#include <hip/hip_runtime.h>
#include <hip/hip_bf16.h>
#include <cstdint>
#include <cstddef>

// Problem constants (from reference)
#define F0v   2048
#define F1v   2304
#define F2v   2560
#define E1v   256
#define E2v   256
#define BROWS 8192
#define ODIM  1024
#define NNZv  262144
#define NBv   1024

typedef __bf16 bf16x8 __attribute__((ext_vector_type(8)));
typedef float floatx4 __attribute__((ext_vector_type(4)));

__device__ __forceinline__ unsigned short f2bf(float f) {
  unsigned int u = __float_as_uint(f);
  u += 0x7FFFu + ((u >> 16) & 1u);   // round-to-nearest-even
  return (unsigned short)(u >> 16);
}

__device__ __forceinline__ void async_ld16(const void* g, void* l) {
  __builtin_amdgcn_global_load_lds(
      (const __attribute__((address_space(1))) unsigned int*)g,
      (__attribute__((address_space(3))) unsigned int*)l, 16, 0, 0);
}

// ---------------------------------------------------------------------------
// Kernel 1 (fused pre-pass), restructured: barrier-free, LDS-free.
//   blocks [0, 1024): COO scatter-add of W and bias (atomics).
//   blocks [1024, 3072): h construction, ONE WAVE PER ROW (4 rows/block).
// Rationale: old version used one block per row with an LDS round-trip and a
// __syncthreads between an 8 KB load phase and a 1 KB gather phase — each
// block serialized on one HBM round-trip (latency-bound, ~2.5x the BW floor).
// Here 8192 independent row-waves (~one resident generation chip-wide) stream
// x->h with no barriers; embed gathers hit L1/L2 since the row was just read.
// ---------------------------------------------------------------------------
__global__ __launch_bounds__(256) void pre_kernel(
    const float* __restrict__ x, const float* __restrict__ e1w,
    const float* __restrict__ e2w, const int* __restrict__ e1p,
    const int* __restrict__ e2p, unsigned short* __restrict__ h,
    const int* __restrict__ wr, const int* __restrict__ wc,
    const float* __restrict__ wv, const int* __restrict__ bidx,
    const float* __restrict__ bv, float* __restrict__ Wd,
    float* __restrict__ bias) {
  const int tid = threadIdx.x;

  if (blockIdx.x < NNZv / 256) {          // scatter blocks first (long-tail atomics start early)
    int gid = blockIdx.x * 256 + tid;
    atomicAdd(&Wd[(size_t)wr[gid] * F2v + wc[gid]], wv[gid]);
    if (gid < NBv) atomicAdd(&bias[bidx[gid]], bv[gid]);
    return;
  }

  const int row  = (blockIdx.x - NNZv / 256) * 4 + (tid >> 6);
  const int lane = tid & 63;
  const float* xr = x + (size_t)row * F0v;
  unsigned short* hr = h + (size_t)row * F2v;

  // Main copy: iteration j, lane l handles floats [j*512 + l*8, +8).
  // Per store instruction the wave writes 1 KiB contiguous (perfect coalesce);
  // loads are two consecutive float4 per lane (same pattern as prior kernel).
#pragma unroll
  for (int j = 0; j < 4; ++j) {
    float4 v0 = ((const float4*)xr)[j * 128 + lane * 2];
    float4 v1 = ((const float4*)xr)[j * 128 + lane * 2 + 1];
    union { unsigned short us[8]; uint4 u4; } pk;
    pk.us[0] = f2bf(v0.x); pk.us[1] = f2bf(v0.y);
    pk.us[2] = f2bf(v0.z); pk.us[3] = f2bf(v0.w);
    pk.us[4] = f2bf(v1.x); pk.us[5] = f2bf(v1.y);
    pk.us[6] = f2bf(v1.z); pk.us[7] = f2bf(v1.w);
    ((uint4*)hr)[j * 64 + lane] = pk.u4;
  }

  // Embed tail: lane l owns cols [l*8, l*8+8) of the 512 embed outputs.
  // Two-hop (e2 parent >= F0) folded closed-form: out = relu(relu(x*wa)*wb).
  // Table arrays are ~1-2 KB each -> L1-hot; x-row gathers hit L1/L2.
  union { unsigned short us[8]; uint4 u4; } pe;
#pragma unroll
  for (int j = 0; j < 8; ++j) {
    int c = lane * 8 + j;
    int src; float wa, wb;
    if (c < E1v) {
      src = e1p[c]; wa = e1w[c]; wb = 1.0f;
    } else {
      int c2 = c - E1v;
      int p2 = e2p[c2]; float w2 = e2w[c2];
      if (p2 < F0v) { src = p2;        wa = w2;     wb = 1.0f; }
      else { int q = p2 - F0v; src = e1p[q]; wa = e1w[q]; wb = w2; }
    }
    float a = fmaxf(fmaxf(xr[src] * wa, 0.0f) * wb, 0.0f);
    pe.us[j] = f2bf(a);
  }
  ((uint4*)(hr + F0v))[lane] = pe.u4;
}

// ---------------------------------------------------------------------------
// Kernel 2: W f32 -> bf16 (8 elems/thread)
// ---------------------------------------------------------------------------
__global__ __launch_bounds__(256) void convert_kernel(
    const float* __restrict__ Wd, unsigned short* __restrict__ Wb) {
  int gid = blockIdx.x * 256 + threadIdx.x;
  const float4* src = (const float4*)Wd;
  float4 a = src[gid * 2];
  float4 b = src[gid * 2 + 1];
  union { unsigned short us[8]; uint4 u4; } pk;
  pk.us[0] = f2bf(a.x); pk.us[1] = f2bf(a.y);
  pk.us[2] = f2bf(a.z); pk.us[3] = f2bf(a.w);
  pk.us[4] = f2bf(b.x); pk.us[5] = f2bf(b.y);
  pk.us[6] = f2bf(b.z); pk.us[7] = f2bf(b.w);
  ((uint4*)Wb)[gid] = pk.u4;
}

// ---------------------------------------------------------------------------
// Kernel 3: C = h @ W^T + bias.  128x128 tile, BK=64 dbuf, 256 threads
// (4 waves, 2x2), wave-tile 64x64 = acc[4][4] of 16x16x32 bf16 MFMA.
// Empirical conflict law (R1/R2/R5 = 4 extra cyc/read; R3/R4 = 0): fragment
// reads must keep the R3 pattern class — 16-row span (r16) with quad in the
// seg XOR: seg = (kk*4+quad)^(r16&7). 8 reads serve 16 MFMAs per kk (same
// FLOP/byte as the 32x32 path) without its 32-row-span conflict penalty.
// LDS 64 KB -> 2 blocks/CU; grid 512 -> barrier phases interleave.
// ---------------------------------------------------------------------------
#define BM 128
#define BN 128
#define BK 64

__global__ __launch_bounds__(256) void gemm_bt_kernel(
    const unsigned short* __restrict__ A,
    const unsigned short* __restrict__ Bw,
    const float* __restrict__ bias,
    float* __restrict__ C) {
  __shared__ unsigned short As[2][BM * BK];   // 2 x 16 KB
  __shared__ unsigned short Bs[2][BN * BK];   // 2 x 16 KB
  const int tid = threadIdx.x;
  const int wave = tid >> 6;      // 0..3
  const int lane = tid & 63;

  // XCD swizzle: grid (8, 64); id%8 = XCD. XCD k owns M-tiles [8k,8k+8).
  const int id = blockIdx.y * 8 + blockIdx.x;
  const int ty = (id & 7) * 8 + ((id >> 3) & 7);   // M-tile 0..63
  const int tx = id >> 6;                          // N-tile 0..7
  const int m0 = ty * BM;
  const int n0 = tx * BN;
  const int wm = wave >> 1;       // 0..1  (64-row half of M)
  const int wn = wave & 1;        // 0..1  (64-col half of N)
  const int quad = lane >> 4;     // 0..3
  const int r16 = lane & 15;
  const int r7 = r16 & 7;

  // Staging: chunk = 8 rows x 64 cols (1 KiB); A,B each 16 chunks; wave w
  // stages chunks {4w..4w+3} of both. Lane L: row L/8, stored seg L%8,
  // sourcing global seg (L%8)^((L/8)&7)  [XOR swizzle, verified R3/R5].
  const int lrow = lane >> 3;                 // 0..7 within chunk
  const int gseg = ((lane & 7) ^ (lrow & 7));
  const unsigned short* gA = A + (size_t)(m0 + wave * 32 + lrow) * F2v + gseg * 8;
  const unsigned short* gB = Bw + (size_t)(n0 + wave * 32 + lrow) * F2v + gseg * 8;
  const int lbase = wave * 2048;              // 4 chunks x 512 elems

  floatx4 acc[4][4];
  floatx4 zz = {0.f, 0.f, 0.f, 0.f};
#pragma unroll
  for (int i = 0; i < 4; ++i)
#pragma unroll
    for (int j = 0; j < 4; ++j) acc[i][j] = zz;

  // prologue: stage k-block 0 into buffer 0
#pragma unroll
  for (int c = 0; c < 4; ++c) {
    async_ld16(gA + (size_t)c * 8 * F2v, &As[0][lbase + c * 512]);
    async_ld16(gB + (size_t)c * 8 * F2v, &Bs[0][lbase + c * 512]);
  }

  for (int k0 = 0; k0 < F2v; k0 += BK) {
    const int pb = (k0 >> 6) & 1;
    __syncthreads();   // drains this buffer's loads; frees other buffer
    if (k0 + BK < F2v) {
      const int nb = pb ^ 1;
#pragma unroll
      for (int c = 0; c < 4; ++c) {
        async_ld16(gA + (k0 + BK) + (size_t)c * 8 * F2v, &As[nb][lbase + c * 512]);
        async_ld16(gB + (k0 + BK) + (size_t)c * 8 * F2v, &Bs[nb][lbase + c * 512]);
      }
    }

    // 2 k-steps of 32; fragment (row, k-seg kk*4+quad) stored at
    // seg = (kk*4+quad)^(row&7); row&7 == r16&7 (bases are x16 multiples).
#pragma unroll
    for (int kk = 0; kk < 2; ++kk) {
      const int sseg = (((kk * 4 + quad) ^ r7) * 8);
      bf16x8 af[4], bfr[4];
#pragma unroll
      for (int mi = 0; mi < 4; ++mi) {
        int row = wm * 64 + mi * 16 + r16;
        af[mi] = *(const bf16x8*)&As[pb][row * BK + sseg];
      }
#pragma unroll
      for (int ni = 0; ni < 4; ++ni) {
        int row = wn * 64 + ni * 16 + r16;
        bfr[ni] = *(const bf16x8*)&Bs[pb][row * BK + sseg];
      }
#pragma unroll
      for (int mi = 0; mi < 4; ++mi)
#pragma unroll
        for (int ni = 0; ni < 4; ++ni)
          acc[mi][ni] = __builtin_amdgcn_mfma_f32_16x16x32_bf16(
              af[mi], bfr[ni], acc[mi][ni], 0, 0, 0);
    }
  }

  // Epilogue: C/D layout col = lane&15, row = quad*4 + reg (m89/m91 verified)
#pragma unroll
  for (int ni = 0; ni < 4; ++ni) {
    int col = n0 + wn * 64 + ni * 16 + r16;
    float bc = bias[col];
#pragma unroll
    for (int mi = 0; mi < 4; ++mi) {
      int row = m0 + wm * 64 + mi * 16 + quad * 4;
#pragma unroll
      for (int rg = 0; rg < 4; ++rg)
        C[(size_t)(row + rg) * ODIM + col] = acc[mi][ni][rg] + bc;
    }
  }
}

// ---------------------------------------------------------------------------
extern "C" void kernel_launch(void* const* d_in, const int* in_sizes, int n_in,
                              void* d_out, int out_size, void* d_ws, size_t ws_size,
                              hipStream_t stream) {
  const float* x    = (const float*)d_in[0];
  const float* e1w  = (const float*)d_in[1];
  const float* e2w  = (const float*)d_in[2];
  const float* wv   = (const float*)d_in[3];
  const float* bv   = (const float*)d_in[4];
  const int*   e1p  = (const int*)d_in[5];
  const int*   e2p  = (const int*)d_in[6];
  const int*   wr   = (const int*)d_in[7];
  const int*   wc   = (const int*)d_in[8];
  const int*   bidx = (const int*)d_in[9];
  float* out = (float*)d_out;

  // Workspace carve (total ~57.7 MB)
  char* ws = (char*)d_ws;
  const size_t h_bytes  = (size_t)BROWS * F2v * 2;        // 41,943,040
  const size_t wd_bytes = (size_t)ODIM * F2v * 4;         // 10,485,760
  const size_t b_bytes  = (size_t)ODIM * 4;               // 4,096
  unsigned short* h   = (unsigned short*)ws;
  float* Wd           = (float*)(ws + h_bytes);
  float* bias         = (float*)(ws + h_bytes + wd_bytes);
  unsigned short* Wb  = (unsigned short*)(ws + h_bytes + wd_bytes + b_bytes);

  hipMemsetAsync(Wd, 0, wd_bytes + b_bytes, stream);
  pre_kernel<<<NNZv / 256 + BROWS / 4, 256, 0, stream>>>(
      x, e1w, e2w, e1p, e2p, h, wr, wc, wv, bidx, bv, Wd, bias);
  convert_kernel<<<(ODIM * F2v / 8) / 256, 256, 0, stream>>>(Wd, Wb);
  gemm_bt_kernel<<<dim3(ODIM / BN, BROWS / BM), 256, 0, stream>>>(h, Wb, bias, out);
}

// Round 2
// 190.606 us; speedup vs baseline: 1.0892x; 1.0892x over previous
//
#include <hip/hip_runtime.h>
#include <hip/hip_bf16.h>
#include <cstdint>
#include <cstddef>

// Problem constants (from reference)
#define F0v   2048
#define F1v   2304
#define F2v   2560
#define E1v   256
#define E2v   256
#define BROWS 8192
#define ODIM  1024
#define NNZv  262144
#define NBv   1024

typedef __bf16 bf16x8 __attribute__((ext_vector_type(8)));
typedef float floatx4 __attribute__((ext_vector_type(4)));

__device__ __forceinline__ unsigned short f2bf(float f) {
  unsigned int u = __float_as_uint(f);
  u += 0x7FFFu + ((u >> 16) & 1u);   // round-to-nearest-even
  return (unsigned short)(u >> 16);
}

__device__ __forceinline__ void async_ld16(const void* g, void* l) {
  __builtin_amdgcn_global_load_lds(
      (const __attribute__((address_space(1))) unsigned int*)g,
      (__attribute__((address_space(3))) unsigned int*)l, 16, 0, 0);
}

// ---------------------------------------------------------------------------
// Kernel 1 (fused): REVERTED to the proven round-0 version. Blocks [0,8192)
// build h rows (LDS-staged row -> gathers are LDS-hits; one barrier); blocks
// [8192,9216) do the COO scatter-add. The wave-per-row global-gather variant
// regressed (+24 MB HBM over-fetch, 2.7 TB/s): gathers must be LDS-served.
// ---------------------------------------------------------------------------
__global__ __launch_bounds__(256) void fused_pre_kernel(
    const float* __restrict__ x, const float* __restrict__ e1w,
    const float* __restrict__ e2w, const int* __restrict__ e1p,
    const int* __restrict__ e2p, unsigned short* __restrict__ h,
    const int* __restrict__ wr, const int* __restrict__ wc,
    const float* __restrict__ wv, const int* __restrict__ bidx,
    const float* __restrict__ bv, float* __restrict__ Wd,
    float* __restrict__ bias) {
  __shared__ float xrow[F0v];
  __shared__ int   tsrc[E1v + E2v];
  __shared__ float twa[E1v + E2v];
  __shared__ float twb[E1v + E2v];
  const int tid = threadIdx.x;

  if (blockIdx.x >= BROWS) {
    int gid = (blockIdx.x - BROWS) * 256 + tid;
    if (gid < NNZv)
      atomicAdd(&Wd[(size_t)wr[gid] * F2v + wc[gid]], wv[gid]);
    if (gid < NBv)
      atomicAdd(&bias[bidx[gid]], bv[gid]);
    return;
  }

  const int b = blockIdx.x;
  const float* xr = x + (size_t)b * F0v;
  unsigned short* hr = h + (size_t)b * F2v;

  {
    tsrc[tid] = e1p[tid]; twa[tid] = e1w[tid]; twb[tid] = 1.0f;
    int p2 = e2p[tid]; float w2 = e2w[tid];
    if (p2 < F0v) {
      tsrc[E1v + tid] = p2;  twa[E1v + tid] = w2;  twb[E1v + tid] = 1.0f;
    } else {
      int q = p2 - F0v;
      tsrc[E1v + tid] = e1p[q]; twa[E1v + tid] = e1w[q]; twb[E1v + tid] = w2;
    }
  }

  float4 v0 = ((const float4*)xr)[tid * 2];
  float4 v1 = ((const float4*)xr)[tid * 2 + 1];
  ((float4*)xrow)[tid * 2] = v0;
  ((float4*)xrow)[tid * 2 + 1] = v1;
  union { unsigned short us[8]; uint4 u4; } pk;
  pk.us[0] = f2bf(v0.x); pk.us[1] = f2bf(v0.y);
  pk.us[2] = f2bf(v0.z); pk.us[3] = f2bf(v0.w);
  pk.us[4] = f2bf(v1.x); pk.us[5] = f2bf(v1.y);
  pk.us[6] = f2bf(v1.z); pk.us[7] = f2bf(v1.w);
  ((uint4*)hr)[tid] = pk.u4;
  __syncthreads();

  int j0 = tid * 2;
  float a0 = fmaxf(fmaxf(xrow[tsrc[j0]] * twa[j0], 0.0f) * twb[j0], 0.0f);
  float a1 = fmaxf(fmaxf(xrow[tsrc[j0 + 1]] * twa[j0 + 1], 0.0f) * twb[j0 + 1], 0.0f);
  unsigned int packed = (unsigned int)f2bf(a0) | ((unsigned int)f2bf(a1) << 16);
  ((unsigned int*)(hr + F0v))[tid] = packed;
}

// ---------------------------------------------------------------------------
// Kernel 2: W f32 -> bf16 (8 elems/thread)
// ---------------------------------------------------------------------------
__global__ __launch_bounds__(256) void convert_kernel(
    const float* __restrict__ Wd, unsigned short* __restrict__ Wb) {
  int gid = blockIdx.x * 256 + threadIdx.x;
  const float4* src = (const float4*)Wd;
  float4 a = src[gid * 2];
  float4 b = src[gid * 2 + 1];
  union { unsigned short us[8]; uint4 u4; } pk;
  pk.us[0] = f2bf(a.x); pk.us[1] = f2bf(a.y);
  pk.us[2] = f2bf(a.z); pk.us[3] = f2bf(a.w);
  pk.us[4] = f2bf(b.x); pk.us[5] = f2bf(b.y);
  pk.us[6] = f2bf(b.z); pk.us[7] = f2bf(b.w);
  ((uint4*)Wb)[gid] = pk.u4;
}

// ---------------------------------------------------------------------------
// Kernel 3: C = h @ W^T + bias.  8-phase counted-vmcnt schedule (T3+T4+T5).
// BM=256 x BN=128, BK=64, 512 threads (8 waves, 4M x 2N), wave-tile 64x64 =
// acc[4][4] of 16x16x32 bf16 MFMA.  TRIPLE-buffered LDS (3 x 48 KB): tile
// T+2's global_load_lds target a buffer whose old tile (T-1) was fully
// consumed one whole K-tile earlier, barrier-separated -> no fine-grained
// write/read races by construction.  Per iteration (2 K-tiles): 8 phases of
// {ds_read frag-quadrant; 2 stage-issues; barrier; 8 MFMA @prio1; barrier}.
// vmcnt(6) only at phases 4 & 8 (3 half-tiles in flight, >=3-phase flight).
// Same verified XOR-swizzle law as before: stored[r][s] = global seg
// s^(r&7); frag read seg = (kk*4+quad)^(r16&7) -> 0 bank conflicts (R3).
// Grid 8 x 32 = 256 blocks = 1 block/CU; LDS 144 KB dynamic.
// ---------------------------------------------------------------------------
#define BM 256
#define BN 128
#define BK 64
#define NT 40                 // K-tiles = F2v / BK
#define BUFE 24576            // elems per buffer: (256+128)*64
#define AOFF 16384            // B-matrix offset within buffer (elems)

#define STA(t, buf, u) \
  async_ld16(gA + (size_t)(u) * 64 * F2v + (t) * BK, \
             &lds[(buf) * BUFE + (u) * 4096 + tid * 8])
#define STB(t, buf, u) \
  async_ld16(gB + (size_t)(u) * 64 * F2v + (t) * BK, \
             &lds[(buf) * BUFE + AOFF + (u) * 4096 + tid * 8])

#define LDA(buf, mi, kk) \
  (*(const bf16x8*)&lds[(buf) * BUFE + rowA[mi] + segq[kk]])
#define LDB(buf, ni, kk) \
  (*(const bf16x8*)&lds[(buf) * BUFE + AOFF + rowB[ni] + segq[kk]])

#define MF(mi, ni) \
  acc[mi][ni] = __builtin_amdgcn_mfma_f32_16x16x32_bf16(af[mi][0], bfr[ni][0], acc[mi][ni], 0, 0, 0); \
  acc[mi][ni] = __builtin_amdgcn_mfma_f32_16x16x32_bf16(af[mi][1], bfr[ni][1], acc[mi][ni], 0, 0, 0);

#define BAR() __builtin_amdgcn_s_barrier()
#define PRIO1() __builtin_amdgcn_s_setprio(1)
#define PRIO0() __builtin_amdgcn_s_setprio(0)

__global__ __launch_bounds__(512, 2) void gemm_bt_kernel(
    const unsigned short* __restrict__ A,
    const unsigned short* __restrict__ Bw,
    const float* __restrict__ bias,
    float* __restrict__ C) {
  extern __shared__ unsigned short lds[];
  const int tid  = threadIdx.x;
  const int wave = tid >> 6;      // 0..7
  const int lane = tid & 63;
  const int wm = wave >> 1;       // 0..3 (64-row quarter of M)
  const int wn = wave & 1;        // 0..1 (64-col half of N)
  const int quad = lane >> 4;     // 0..3
  const int r16 = lane & 15;
  const int r7 = r16 & 7;

  const int m0 = blockIdx.y * BM;   // gridDim=(8,32): bx=N-tile -> XCD=id%8
  const int n0 = blockIdx.x * BN;   // shares the W panel per XCD (L2-hot)

  // Staging: call = 64-row unit (8 KB = 512 thr x 16 B). Thread tid: row
  // tid/8 within unit, stored seg tid%8, sourcing global seg (tid%8)^(row&7)
  // (pre-swizzled source, linear LDS dest = wave-uniform base + lane*16).
  const int srow = tid >> 3;                       // 0..63
  const int sseg8 = ((tid & 7) ^ (srow & 7)) * 8;
  const unsigned short* gA = A  + (size_t)(m0 + srow) * F2v + sseg8;
  const unsigned short* gB = Bw + (size_t)(n0 + srow) * F2v + sseg8;

  // Frag-read invariants
  int rowA[4], rowB[4], segq[2];
#pragma unroll
  for (int i = 0; i < 4; ++i) {
    rowA[i] = (wm * 64 + i * 16 + r16) * 64;
    rowB[i] = (wn * 64 + i * 16 + r16) * 64;
  }
  segq[0] = ((quad) ^ r7) * 8;
  segq[1] = ((4 + quad) ^ r7) * 8;

  floatx4 acc[4][4];
  floatx4 zz = {0.f, 0.f, 0.f, 0.f};
#pragma unroll
  for (int i = 0; i < 4; ++i)
#pragma unroll
    for (int j = 0; j < 4; ++j) acc[i][j] = zz;

  bf16x8 af[4][2], bfr[4][2];

  // Prologue: stage tiles 0 -> buf0, 1 -> buf1 (6 calls each)
#pragma unroll
  for (int u = 0; u < 4; ++u) STA(0, 0, u);
  STB(0, 0, 0); STB(0, 0, 1);
#pragma unroll
  for (int u = 0; u < 4; ++u) STA(1, 1, u);
  STB(1, 1, 0); STB(1, 1, 1);
  asm volatile("s_waitcnt vmcnt(6)" ::: "memory");  // tile 0 landed
  BAR();

  int c0 = 0, c1 = 1, c2 = 2;   // buffers of tiles 2i, 2i+1, 2i+2
  for (int i = 0; i < 20; ++i) {
    const int t2 = 2 * i + 2, t3 = 2 * i + 3;
    const bool s2 = t2 < NT, s3 = t3 < NT;

    // ===== K-tile t0 = 2i  (buffer c0) =====
    // ph1 (m01,n01)
    af[0][0] = LDA(c0, 0, 0); af[0][1] = LDA(c0, 0, 1);
    af[1][0] = LDA(c0, 1, 0); af[1][1] = LDA(c0, 1, 1);
    bfr[0][0] = LDB(c0, 0, 0); bfr[0][1] = LDB(c0, 0, 1);
    bfr[1][0] = LDB(c0, 1, 0); bfr[1][1] = LDB(c0, 1, 1);
    if (s2) { STA(t2, c2, 0); STA(t2, c2, 1); }
    BAR();
    PRIO1(); MF(0, 0) MF(0, 1) MF(1, 0) MF(1, 1) PRIO0();
    BAR();
    // ph2 (m23,n01)
    af[2][0] = LDA(c0, 2, 0); af[2][1] = LDA(c0, 2, 1);
    af[3][0] = LDA(c0, 3, 0); af[3][1] = LDA(c0, 3, 1);
    if (s2) { STA(t2, c2, 2); STA(t2, c2, 3); }
    BAR();
    PRIO1(); MF(2, 0) MF(2, 1) MF(3, 0) MF(3, 1) PRIO0();
    BAR();
    // ph3 (m01,n23)
    bfr[2][0] = LDB(c0, 2, 0); bfr[2][1] = LDB(c0, 2, 1);
    bfr[3][0] = LDB(c0, 3, 0); bfr[3][1] = LDB(c0, 3, 1);
    if (s2) { STB(t2, c2, 0); STB(t2, c2, 1); }
    BAR();
    PRIO1(); MF(0, 2) MF(0, 3) MF(1, 2) MF(1, 3) PRIO0();
    BAR();
    // ph4 (m23,n23) — all frags cached
    PRIO1(); MF(2, 2) MF(2, 3) MF(3, 2) MF(3, 3) PRIO0();
    if (i < 19) asm volatile("s_waitcnt vmcnt(6)" ::: "memory");  // t1 landed
    else        asm volatile("s_waitcnt vmcnt(0)" ::: "memory");
    BAR();

    // ===== K-tile t1 = 2i+1  (buffer c1) =====
    // t3 -> buffer (2i+3)%3 == c0: old data (t0) fully ds_read by ph3's
    // barrier, so staging from ph5 on is race-free.
    // ph5
    af[0][0] = LDA(c1, 0, 0); af[0][1] = LDA(c1, 0, 1);
    af[1][0] = LDA(c1, 1, 0); af[1][1] = LDA(c1, 1, 1);
    bfr[0][0] = LDB(c1, 0, 0); bfr[0][1] = LDB(c1, 0, 1);
    bfr[1][0] = LDB(c1, 1, 0); bfr[1][1] = LDB(c1, 1, 1);
    if (s3) { STA(t3, c0, 0); STA(t3, c0, 1); }
    BAR();
    PRIO1(); MF(0, 0) MF(0, 1) MF(1, 0) MF(1, 1) PRIO0();
    BAR();
    // ph6
    af[2][0] = LDA(c1, 2, 0); af[2][1] = LDA(c1, 2, 1);
    af[3][0] = LDA(c1, 3, 0); af[3][1] = LDA(c1, 3, 1);
    if (s3) { STA(t3, c0, 2); STA(t3, c0, 3); }
    BAR();
    PRIO1(); MF(2, 0) MF(2, 1) MF(3, 0) MF(3, 1) PRIO0();
    BAR();
    // ph7
    bfr[2][0] = LDB(c1, 2, 0); bfr[2][1] = LDB(c1, 2, 1);
    bfr[3][0] = LDB(c1, 3, 0); bfr[3][1] = LDB(c1, 3, 1);
    if (s3) { STB(t3, c0, 0); STB(t3, c0, 1); }
    BAR();
    PRIO1(); MF(0, 2) MF(0, 3) MF(1, 2) MF(1, 3) PRIO0();
    BAR();
    // ph8
    PRIO1(); MF(2, 2) MF(2, 3) MF(3, 2) MF(3, 3) PRIO0();
    if (i < 19) asm volatile("s_waitcnt vmcnt(6)" ::: "memory");  // t2 landed
    BAR();

    // rotate buffers: tiles (2i+2, 2i+3, 2i+4) -> (c2, c0, c1)
    int tmp = c0; c0 = c2; c2 = c1; c1 = tmp;
  }

  // Epilogue: C/D layout col = lane&15, row = quad*4 + reg (m89/m91 verified)
#pragma unroll
  for (int ni = 0; ni < 4; ++ni) {
    int col = n0 + wn * 64 + ni * 16 + r16;
    float bc = bias[col];
#pragma unroll
    for (int mi = 0; mi < 4; ++mi) {
      int row = m0 + wm * 64 + mi * 16 + quad * 4;
#pragma unroll
      for (int rg = 0; rg < 4; ++rg)
        C[(size_t)(row + rg) * ODIM + col] = acc[mi][ni][rg] + bc;
    }
  }
}

// ---------------------------------------------------------------------------
extern "C" void kernel_launch(void* const* d_in, const int* in_sizes, int n_in,
                              void* d_out, int out_size, void* d_ws, size_t ws_size,
                              hipStream_t stream) {
  const float* x    = (const float*)d_in[0];
  const float* e1w  = (const float*)d_in[1];
  const float* e2w  = (const float*)d_in[2];
  const float* wv   = (const float*)d_in[3];
  const float* bv   = (const float*)d_in[4];
  const int*   e1p  = (const int*)d_in[5];
  const int*   e2p  = (const int*)d_in[6];
  const int*   wr   = (const int*)d_in[7];
  const int*   wc   = (const int*)d_in[8];
  const int*   bidx = (const int*)d_in[9];
  float* out = (float*)d_out;

  // Workspace carve (total ~57.7 MB)
  char* ws = (char*)d_ws;
  const size_t h_bytes  = (size_t)BROWS * F2v * 2;        // 41,943,040
  const size_t wd_bytes = (size_t)ODIM * F2v * 4;         // 10,485,760
  const size_t b_bytes  = (size_t)ODIM * 4;               // 4,096
  unsigned short* h   = (unsigned short*)ws;
  float* Wd           = (float*)(ws + h_bytes);
  float* bias         = (float*)(ws + h_bytes + wd_bytes);
  unsigned short* Wb  = (unsigned short*)(ws + h_bytes + wd_bytes + b_bytes);

  hipMemsetAsync(Wd, 0, wd_bytes + b_bytes, stream);
  fused_pre_kernel<<<BROWS + NNZv / 256, 256, 0, stream>>>(
      x, e1w, e2w, e1p, e2p, h, wr, wc, wv, bidx, bv, Wd, bias);
  convert_kernel<<<(ODIM * F2v / 8) / 256, 256, 0, stream>>>(Wd, Wb);

  // 144 KB dynamic LDS (3 x 48 KB triple buffer) — raise the cap, then launch
  hipFuncSetAttribute(reinterpret_cast<const void*>(gemm_bt_kernel),
                      hipFuncAttributeMaxDynamicSharedMemorySize, 3 * BUFE * 2);
  gemm_bt_kernel<<<dim3(ODIM / BN, BROWS / BM), 512, 3 * BUFE * 2, stream>>>(
      h, Wb, bias, out);
}

// Round 3
// 179.951 us; speedup vs baseline: 1.1537x; 1.0592x over previous
//
#include <hip/hip_runtime.h>
#include <hip/hip_bf16.h>
#include <cstdint>
#include <cstddef>

// Problem constants (from reference)
#define F0v   2048
#define F1v   2304
#define F2v   2560
#define E1v   256
#define E2v   256
#define BROWS 8192
#define ODIM  1024
#define NNZv  262144
#define NBv   1024

typedef __bf16 bf16x8 __attribute__((ext_vector_type(8)));
typedef float floatx4 __attribute__((ext_vector_type(4)));

__device__ __forceinline__ unsigned short f2bf(float f) {
  unsigned int u = __float_as_uint(f);
  u += 0x7FFFu + ((u >> 16) & 1u);   // round-to-nearest-even
  return (unsigned short)(u >> 16);
}

__device__ __forceinline__ void async_ld16(const void* g, void* l) {
  __builtin_amdgcn_global_load_lds(
      (const __attribute__((address_space(1))) unsigned int*)g,
      (__attribute__((address_space(3))) unsigned int*)l, 16, 0, 0);
}

// ---------------------------------------------------------------------------
// Kernel 1 (fused): proven round-0 version. Blocks [0,8192) build h rows
// (LDS-staged row -> gathers are LDS-hits; one barrier); blocks [8192,9216)
// do the COO scatter-add. (Wave-per-row global-gather variant regressed:
// +24 MB HBM over-fetch — gathers must be LDS-served.)
// ---------------------------------------------------------------------------
__global__ __launch_bounds__(256) void fused_pre_kernel(
    const float* __restrict__ x, const float* __restrict__ e1w,
    const float* __restrict__ e2w, const int* __restrict__ e1p,
    const int* __restrict__ e2p, unsigned short* __restrict__ h,
    const int* __restrict__ wr, const int* __restrict__ wc,
    const float* __restrict__ wv, const int* __restrict__ bidx,
    const float* __restrict__ bv, float* __restrict__ Wd,
    float* __restrict__ bias) {
  __shared__ float xrow[F0v];
  __shared__ int   tsrc[E1v + E2v];
  __shared__ float twa[E1v + E2v];
  __shared__ float twb[E1v + E2v];
  const int tid = threadIdx.x;

  if (blockIdx.x >= BROWS) {
    int gid = (blockIdx.x - BROWS) * 256 + tid;
    if (gid < NNZv)
      atomicAdd(&Wd[(size_t)wr[gid] * F2v + wc[gid]], wv[gid]);
    if (gid < NBv)
      atomicAdd(&bias[bidx[gid]], bv[gid]);
    return;
  }

  const int b = blockIdx.x;
  const float* xr = x + (size_t)b * F0v;
  unsigned short* hr = h + (size_t)b * F2v;

  {
    tsrc[tid] = e1p[tid]; twa[tid] = e1w[tid]; twb[tid] = 1.0f;
    int p2 = e2p[tid]; float w2 = e2w[tid];
    if (p2 < F0v) {
      tsrc[E1v + tid] = p2;  twa[E1v + tid] = w2;  twb[E1v + tid] = 1.0f;
    } else {
      int q = p2 - F0v;
      tsrc[E1v + tid] = e1p[q]; twa[E1v + tid] = e1w[q]; twb[E1v + tid] = w2;
    }
  }

  float4 v0 = ((const float4*)xr)[tid * 2];
  float4 v1 = ((const float4*)xr)[tid * 2 + 1];
  ((float4*)xrow)[tid * 2] = v0;
  ((float4*)xrow)[tid * 2 + 1] = v1;
  union { unsigned short us[8]; uint4 u4; } pk;
  pk.us[0] = f2bf(v0.x); pk.us[1] = f2bf(v0.y);
  pk.us[2] = f2bf(v0.z); pk.us[3] = f2bf(v0.w);
  pk.us[4] = f2bf(v1.x); pk.us[5] = f2bf(v1.y);
  pk.us[6] = f2bf(v1.z); pk.us[7] = f2bf(v1.w);
  ((uint4*)hr)[tid] = pk.u4;
  __syncthreads();

  int j0 = tid * 2;
  float a0 = fmaxf(fmaxf(xrow[tsrc[j0]] * twa[j0], 0.0f) * twb[j0], 0.0f);
  float a1 = fmaxf(fmaxf(xrow[tsrc[j0 + 1]] * twa[j0 + 1], 0.0f) * twb[j0 + 1], 0.0f);
  unsigned int packed = (unsigned int)f2bf(a0) | ((unsigned int)f2bf(a1) << 16);
  ((unsigned int*)(hr + F0v))[tid] = packed;
}

// ---------------------------------------------------------------------------
// Kernel 2: W f32 -> bf16 (8 elems/thread)
// ---------------------------------------------------------------------------
__global__ __launch_bounds__(256) void convert_kernel(
    const float* __restrict__ Wd, unsigned short* __restrict__ Wb) {
  int gid = blockIdx.x * 256 + threadIdx.x;
  const float4* src = (const float4*)Wd;
  float4 a = src[gid * 2];
  float4 b = src[gid * 2 + 1];
  union { unsigned short us[8]; uint4 u4; } pk;
  pk.us[0] = f2bf(a.x); pk.us[1] = f2bf(a.y);
  pk.us[2] = f2bf(a.z); pk.us[3] = f2bf(a.w);
  pk.us[4] = f2bf(b.x); pk.us[5] = f2bf(b.y);
  pk.us[6] = f2bf(b.z); pk.us[7] = f2bf(b.w);
  ((uint4*)Wb)[gid] = pk.u4;
}

// ---------------------------------------------------------------------------
// Kernel 3: C = h @ W^T + bias.  8-phase counted-vmcnt schedule (T3+T4+T5),
// BM=256 x BN=128, BK=64, 512 threads (8 waves, 4M x 2N), triple-buffered
// LDS (3 x 48 KB) — race-free by construction (stage target's old tile was
// fully consumed one K-tile earlier, barrier-separated).
//
// ROUND-2 FIX: XCD-aware block decode. Round-2's mapping gave each XCD an
// N-strip -> the whole 42 MB h streamed through every XCD's private L2
// (FETCH 166 MB, 3.8 TB/s, memory-bound at 53 µs). Now XCD k owns M-tiles
// [4k,4k+4) (5.2 MB h panel, fetched once, L2/L3-resident); W re-reads are
// L3-served. Per-K-step live set/XCD ~262 KB.
// ---------------------------------------------------------------------------
#define BM 256
#define BN 128
#define BK 64
#define NT 40                 // K-tiles = F2v / BK
#define BUFE 24576            // elems per buffer: (256+128)*64
#define AOFF 16384            // B-matrix offset within buffer (elems)

#define STA(t, buf, u) \
  async_ld16(gA + (size_t)(u) * 64 * F2v + (t) * BK, \
             &lds[(buf) * BUFE + (u) * 4096 + tid * 8])
#define STB(t, buf, u) \
  async_ld16(gB + (size_t)(u) * 64 * F2v + (t) * BK, \
             &lds[(buf) * BUFE + AOFF + (u) * 4096 + tid * 8])

#define LDA(buf, mi, kk) \
  (*(const bf16x8*)&lds[(buf) * BUFE + rowA[mi] + segq[kk]])
#define LDB(buf, ni, kk) \
  (*(const bf16x8*)&lds[(buf) * BUFE + AOFF + rowB[ni] + segq[kk]])

#define MF(mi, ni) \
  acc[mi][ni] = __builtin_amdgcn_mfma_f32_16x16x32_bf16(af[mi][0], bfr[ni][0], acc[mi][ni], 0, 0, 0); \
  acc[mi][ni] = __builtin_amdgcn_mfma_f32_16x16x32_bf16(af[mi][1], bfr[ni][1], acc[mi][ni], 0, 0, 0);

#define BAR() __builtin_amdgcn_s_barrier()
#define PRIO1() __builtin_amdgcn_s_setprio(1)
#define PRIO0() __builtin_amdgcn_s_setprio(0)

__global__ __launch_bounds__(512, 2) void gemm_bt_kernel(
    const unsigned short* __restrict__ A,
    const unsigned short* __restrict__ Bw,
    const float* __restrict__ bias,
    float* __restrict__ C) {
  extern __shared__ unsigned short lds[];
  const int tid  = threadIdx.x;
  const int wave = tid >> 6;      // 0..7
  const int lane = tid & 63;
  const int wm = wave >> 1;       // 0..3 (64-row quarter of M)
  const int wn = wave & 1;        // 0..1 (64-col half of N)
  const int quad = lane >> 4;     // 0..3
  const int r16 = lane & 15;
  const int r7 = r16 & 7;

  // XCD-aware decode: 256 blocks, id%8 = XCD. XCD k owns M-tiles [4k,4k+4)
  // x all 8 N-tiles (32 blocks = its 32 CUs, 1 block/CU).
  const int id  = blockIdx.y * 8 + blockIdx.x;
  const int xcd = id & 7;
  const int j   = id >> 3;                  // 0..31 within XCD
  const int m0 = (xcd * 4 + (j & 3)) * BM;  // M-tile 0..31
  const int n0 = (j >> 2) * BN;             // N-tile 0..7

  // Staging: call = 64-row unit (8 KB = 512 thr x 16 B). Thread tid: row
  // tid/8 within unit, stored seg tid%8, sourcing global seg (tid%8)^(row&7)
  // (pre-swizzled source, linear LDS dest = wave-uniform base + lane*16).
  const int srow = tid >> 3;                       // 0..63
  const int sseg8 = ((tid & 7) ^ (srow & 7)) * 8;
  const unsigned short* gA = A  + (size_t)(m0 + srow) * F2v + sseg8;
  const unsigned short* gB = Bw + (size_t)(n0 + srow) * F2v + sseg8;

  // Frag-read invariants
  int rowA[4], rowB[4], segq[2];
#pragma unroll
  for (int i = 0; i < 4; ++i) {
    rowA[i] = (wm * 64 + i * 16 + r16) * 64;
    rowB[i] = (wn * 64 + i * 16 + r16) * 64;
  }
  segq[0] = ((quad) ^ r7) * 8;
  segq[1] = ((4 + quad) ^ r7) * 8;

  floatx4 acc[4][4];
  floatx4 zz = {0.f, 0.f, 0.f, 0.f};
#pragma unroll
  for (int i = 0; i < 4; ++i)
#pragma unroll
    for (int j2 = 0; j2 < 4; ++j2) acc[i][j2] = zz;

  bf16x8 af[4][2], bfr[4][2];

  // Prologue: stage tiles 0 -> buf0, 1 -> buf1 (6 calls each)
#pragma unroll
  for (int u = 0; u < 4; ++u) STA(0, 0, u);
  STB(0, 0, 0); STB(0, 0, 1);
#pragma unroll
  for (int u = 0; u < 4; ++u) STA(1, 1, u);
  STB(1, 1, 0); STB(1, 1, 1);
  asm volatile("s_waitcnt vmcnt(6)" ::: "memory");  // tile 0 landed
  BAR();

  int c0 = 0, c1 = 1, c2 = 2;   // buffers of tiles 2i, 2i+1, 2i+2
  for (int i = 0; i < 20; ++i) {
    const int t2 = 2 * i + 2, t3 = 2 * i + 3;
    const bool s2 = t2 < NT, s3 = t3 < NT;

    // ===== K-tile t0 = 2i  (buffer c0) =====
    // ph1 (m01,n01)
    af[0][0] = LDA(c0, 0, 0); af[0][1] = LDA(c0, 0, 1);
    af[1][0] = LDA(c0, 1, 0); af[1][1] = LDA(c0, 1, 1);
    bfr[0][0] = LDB(c0, 0, 0); bfr[0][1] = LDB(c0, 0, 1);
    bfr[1][0] = LDB(c0, 1, 0); bfr[1][1] = LDB(c0, 1, 1);
    if (s2) { STA(t2, c2, 0); STA(t2, c2, 1); }
    BAR();
    PRIO1(); MF(0, 0) MF(0, 1) MF(1, 0) MF(1, 1) PRIO0();
    BAR();
    // ph2 (m23,n01)
    af[2][0] = LDA(c0, 2, 0); af[2][1] = LDA(c0, 2, 1);
    af[3][0] = LDA(c0, 3, 0); af[3][1] = LDA(c0, 3, 1);
    if (s2) { STA(t2, c2, 2); STA(t2, c2, 3); }
    BAR();
    PRIO1(); MF(2, 0) MF(2, 1) MF(3, 0) MF(3, 1) PRIO0();
    BAR();
    // ph3 (m01,n23)
    bfr[2][0] = LDB(c0, 2, 0); bfr[2][1] = LDB(c0, 2, 1);
    bfr[3][0] = LDB(c0, 3, 0); bfr[3][1] = LDB(c0, 3, 1);
    if (s2) { STB(t2, c2, 0); STB(t2, c2, 1); }
    BAR();
    PRIO1(); MF(0, 2) MF(0, 3) MF(1, 2) MF(1, 3) PRIO0();
    BAR();
    // ph4 (m23,n23) — all frags cached
    PRIO1(); MF(2, 2) MF(2, 3) MF(3, 2) MF(3, 3) PRIO0();
    if (i < 19) asm volatile("s_waitcnt vmcnt(6)" ::: "memory");  // t1 landed
    else        asm volatile("s_waitcnt vmcnt(0)" ::: "memory");
    BAR();

    // ===== K-tile t1 = 2i+1  (buffer c1) =====
    // t3 -> buffer c0: old data (t0) fully ds_read by ph3's barrier.
    // ph5
    af[0][0] = LDA(c1, 0, 0); af[0][1] = LDA(c1, 0, 1);
    af[1][0] = LDA(c1, 1, 0); af[1][1] = LDA(c1, 1, 1);
    bfr[0][0] = LDB(c1, 0, 0); bfr[0][1] = LDB(c1, 0, 1);
    bfr[1][0] = LDB(c1, 1, 0); bfr[1][1] = LDB(c1, 1, 1);
    if (s3) { STA(t3, c0, 0); STA(t3, c0, 1); }
    BAR();
    PRIO1(); MF(0, 0) MF(0, 1) MF(1, 0) MF(1, 1) PRIO0();
    BAR();
    // ph6
    af[2][0] = LDA(c1, 2, 0); af[2][1] = LDA(c1, 2, 1);
    af[3][0] = LDA(c1, 3, 0); af[3][1] = LDA(c1, 3, 1);
    if (s3) { STA(t3, c0, 2); STA(t3, c0, 3); }
    BAR();
    PRIO1(); MF(2, 0) MF(2, 1) MF(3, 0) MF(3, 1) PRIO0();
    BAR();
    // ph7
    bfr[2][0] = LDB(c1, 2, 0); bfr[2][1] = LDB(c1, 2, 1);
    bfr[3][0] = LDB(c1, 3, 0); bfr[3][1] = LDB(c1, 3, 1);
    if (s3) { STB(t3, c0, 0); STB(t3, c0, 1); }
    BAR();
    PRIO1(); MF(0, 2) MF(0, 3) MF(1, 2) MF(1, 3) PRIO0();
    BAR();
    // ph8
    PRIO1(); MF(2, 2) MF(2, 3) MF(3, 2) MF(3, 3) PRIO0();
    if (i < 19) asm volatile("s_waitcnt vmcnt(6)" ::: "memory");  // t2 landed
    BAR();

    // rotate buffers: tiles (2i+2, 2i+3, 2i+4) -> (c2, c0, c1)
    int tmp = c0; c0 = c2; c2 = c1; c1 = tmp;
  }

  // Epilogue: C/D layout col = lane&15, row = quad*4 + reg (m89/m91 verified)
#pragma unroll
  for (int ni = 0; ni < 4; ++ni) {
    int col = n0 + wn * 64 + ni * 16 + r16;
    float bc = bias[col];
#pragma unroll
    for (int mi = 0; mi < 4; ++mi) {
      int row = m0 + wm * 64 + mi * 16 + quad * 4;
#pragma unroll
      for (int rg = 0; rg < 4; ++rg)
        C[(size_t)(row + rg) * ODIM + col] = acc[mi][ni][rg] + bc;
    }
  }
}

// ---------------------------------------------------------------------------
extern "C" void kernel_launch(void* const* d_in, const int* in_sizes, int n_in,
                              void* d_out, int out_size, void* d_ws, size_t ws_size,
                              hipStream_t stream) {
  const float* x    = (const float*)d_in[0];
  const float* e1w  = (const float*)d_in[1];
  const float* e2w  = (const float*)d_in[2];
  const float* wv   = (const float*)d_in[3];
  const float* bv   = (const float*)d_in[4];
  const int*   e1p  = (const int*)d_in[5];
  const int*   e2p  = (const int*)d_in[6];
  const int*   wr   = (const int*)d_in[7];
  const int*   wc   = (const int*)d_in[8];
  const int*   bidx = (const int*)d_in[9];
  float* out = (float*)d_out;

  // Workspace carve (total ~57.7 MB)
  char* ws = (char*)d_ws;
  const size_t h_bytes  = (size_t)BROWS * F2v * 2;        // 41,943,040
  const size_t wd_bytes = (size_t)ODIM * F2v * 4;         // 10,485,760
  const size_t b_bytes  = (size_t)ODIM * 4;               // 4,096
  unsigned short* h   = (unsigned short*)ws;
  float* Wd           = (float*)(ws + h_bytes);
  float* bias         = (float*)(ws + h_bytes + wd_bytes);
  unsigned short* Wb  = (unsigned short*)(ws + h_bytes + wd_bytes + b_bytes);

  hipMemsetAsync(Wd, 0, wd_bytes + b_bytes, stream);
  fused_pre_kernel<<<BROWS + NNZv / 256, 256, 0, stream>>>(
      x, e1w, e2w, e1p, e2p, h, wr, wc, wv, bidx, bv, Wd, bias);
  convert_kernel<<<(ODIM * F2v / 8) / 256, 256, 0, stream>>>(Wd, Wb);

  // 144 KB dynamic LDS (3 x 48 KB triple buffer) — raise the cap, then launch
  hipFuncSetAttribute(reinterpret_cast<const void*>(gemm_bt_kernel),
                      hipFuncAttributeMaxDynamicSharedMemorySize, 3 * BUFE * 2);
  gemm_bt_kernel<<<dim3(ODIM / BN, BROWS / BM), 512, 3 * BUFE * 2, stream>>>(
      h, Wb, bias, out);
}